// Round 6
// baseline (3593.131 us; speedup 1.0000x reference)
//
#include <hip/hip_runtime.h>

typedef _Float16 half2v __attribute__((ext_vector_type(2)));
typedef _Float16 half8v __attribute__((ext_vector_type(8)));
typedef float f32x4 __attribute__((ext_vector_type(4)));

#define S_LEN 2048

static __device__ __forceinline__ unsigned int pk16(float a, float b) {
  half2v h; h[0] = (_Float16)a; h[1] = (_Float16)b;
  return __builtin_bit_cast(unsigned int, h);
}
static __device__ __forceinline__ float uph(unsigned short u) {
  return (float)__builtin_bit_cast(_Float16, u);
}
static __device__ __forceinline__ unsigned short f16bits(float x) {
  return __builtin_bit_cast(unsigned short, (_Float16)x);
}
static __device__ __forceinline__ float sigm(float x) {
  return 1.0f / (1.0f + __expf(-x));
}
static __device__ __forceinline__ float tanh_fast(float x) {
  float e = __expf(2.0f * x);
  return 1.0f - 2.0f / (e + 1.0f);   // safe at +/-inf
}
static __device__ __forceinline__ float sel4(f32x4 v, int b) {
  return (b == 0) ? v[0] : (b == 1) ? v[1] : (b == 2) ? v[2] : v[3];
}

// ---------------------------------------------------------------------------
// Kernel 1: P[m, g*256+j] = f16( x[m,:] . W{g}_x[j,:] + b{g}[j] )  (unchanged)
// ---------------------------------------------------------------------------
__global__ __launch_bounds__(256, 2) void gemm_pre(
    const float* __restrict__ x,
    const float* __restrict__ Wz, const float* __restrict__ bz,
    const float* __restrict__ Wr, const float* __restrict__ br,
    const float* __restrict__ Wc, const float* __restrict__ bc,
    const float* __restrict__ Wh, const float* __restrict__ bh,
    unsigned short* __restrict__ P)
{
  __shared__ __align__(16) char As[128 * 128];
  __shared__ __align__(16) char Bs[128 * 128];
  const int t = threadIdx.x;
  const int lane = t & 63;
  const int wid = t >> 6;
  const int wm = wid >> 1, wn = wid & 1;
  const int n0 = blockIdx.x * 128;
  const int m0 = blockIdx.y * 128;

  f32x4 acc[4][4];
  #pragma unroll
  for (int i = 0; i < 4; ++i)
    #pragma unroll
    for (int jq = 0; jq < 4; ++jq) acc[i][jq] = f32x4{0.f, 0.f, 0.f, 0.f};

  for (int kk = 0; kk < 4; ++kk) {
    __syncthreads();
    #pragma unroll
    for (int it = 0; it < 8; ++it) {
      int fl = it * 256 + t;
      int row = fl >> 4;
      int c4 = fl & 15;
      f32x4 v = *(const f32x4*)(x + (size_t)(m0 + row) * 256 + kk * 64 + c4 * 4);
      uint2 pw; pw.x = pk16(v[0], v[1]); pw.y = pk16(v[2], v[3]);
      *(uint2*)(As + row * 128 + ((c4 * 8) ^ ((row & 7) << 4))) = pw;

      int n = n0 + row;
      int g = n >> 8; int jc = n & 255;
      const float* W = (g == 0) ? Wz : (g == 1) ? Wr : (g == 2) ? Wc : Wh;
      f32x4 wv = *(const f32x4*)(W + jc * 512 + kk * 64 + c4 * 4);
      uint2 qw; qw.x = pk16(wv[0], wv[1]); qw.y = pk16(wv[2], wv[3]);
      *(uint2*)(Bs + row * 128 + ((c4 * 8) ^ ((row & 7) << 4))) = qw;
    }
    __syncthreads();
    #pragma unroll
    for (int k2 = 0; k2 < 2; ++k2) {
      const int kb = k2 * 64 + (lane >> 4) * 16;
      half8v a[4], bfr[4];
      #pragma unroll
      for (int i = 0; i < 4; ++i) {
        int ar = wm * 64 + i * 16 + (lane & 15);
        a[i] = *(const half8v*)(As + ar * 128 + (kb ^ ((ar & 7) << 4)));
        int br2 = wn * 64 + i * 16 + (lane & 15);
        bfr[i] = *(const half8v*)(Bs + br2 * 128 + (kb ^ ((br2 & 7) << 4)));
      }
      #pragma unroll
      for (int i = 0; i < 4; ++i)
        #pragma unroll
        for (int jq = 0; jq < 4; ++jq)
          acc[i][jq] = __builtin_amdgcn_mfma_f32_16x16x32_f16(a[i], bfr[jq], acc[i][jq], 0, 0, 0);
    }
  }
  #pragma unroll
  for (int jq = 0; jq < 4; ++jq) {
    int col = n0 + wn * 64 + jq * 16 + (lane & 15);
    int g = col >> 8; int jc = col & 255;
    const float* bp = (g == 0) ? bz : (g == 1) ? br : (g == 2) ? bc : bh;
    float bias = bp[jc];
    #pragma unroll
    for (int i = 0; i < 4; ++i) {
      int rowb = m0 + wm * 64 + i * 16 + (lane >> 4) * 4;
      #pragma unroll
      for (int r = 0; r < 4; ++r) {
        float vv = acc[i][jq][r] + bias;
        P[(size_t)(rowb + r) * 1024 + col] = f16bits(vv);
      }
    }
  }
}

// ---------------------------------------------------------------------------
// Kernel 2: sequential scan via per-wave MFMA matvecs.
// 64 blocks x 512 threads. Wave w owns z-rows [w*32,+32), r-rows [256+w*32,+32),
// c-rows [w*32,+32) as 6 row-groups of 16; A-frags resident in 192 regs
// (MFMA reads AGPRs directly). B = h (or r*h) replicated across cols: per lane
// one b128 broadcast read per k-chunk. Owner lane (col<4) keeps j0=w*32+khi*4+lb,
// j1=j0+16 entirely in registers: z,r gates, rh, h. 2 barriers/step.
// ---------------------------------------------------------------------------
__global__ __launch_bounds__(512, 1) void gru_scan(
    const float* __restrict__ Wz, const float* __restrict__ Wr,
    const float* __restrict__ Wc,
    unsigned short* P, float* __restrict__ out)
{
  __shared__ __align__(16) unsigned short h_lds[256];
  __shared__ __align__(16) unsigned short rh_lds[256];

  const int t = threadIdx.x;
  const int b = blockIdx.x;
  const int w = t >> 6;
  const int l = t & 63;
  const int col = l & 15;
  const int khi = l >> 4;          // 0..3
  const int lb = l & 3;
  const bool owner = (col < 4);
  const int j0 = w * 32 + khi * 4 + lb;
  const int j1 = j0 + 16;

  // ---- A-fragments: [group][k-chunk]; A[row=R0+col][k=kc*32+khi*8+e]
  half8v wzA[2][8], wrA[2][8], wcA[2][8];
  {
    #pragma unroll
    for (int g = 0; g < 2; ++g) {
      int row = w * 32 + g * 16 + col;
      const float* pz = Wz + row * 512 + 256 + khi * 8;
      const float* pr = Wr + row * 512 + 256 + khi * 8;
      const float* pc = Wc + row * 512 + 256 + khi * 8;
      #pragma unroll
      for (int kc = 0; kc < 8; ++kc) {
        half8v vz, vr, vc;
        #pragma unroll
        for (int e = 0; e < 8; ++e) {
          vz[e] = (_Float16)pz[kc * 32 + e];
          vr[e] = (_Float16)pr[kc * 32 + e];
          vc[e] = (_Float16)pc[kc * 32 + e];
        }
        wzA[g][kc] = vz; wrA[g][kc] = vr; wcA[g][kc] = vc;
      }
    }
  }

  if (t < 128) ((unsigned int*)h_lds)[t] = 0u;

  float h0 = 0.f, h1 = 0.f;
  unsigned short czx0 = 0, czx1 = 0, crx0 = 0, crx1 = 0, ccx0 = 0, ccx1 = 0;
  {
    const unsigned short* pb = P + b * 1024;
    czx0 = pb[j0]; czx1 = pb[j1];
    crx0 = pb[256 + j0]; crx1 = pb[256 + j1];
    ccx0 = pb[512 + j0]; ccx1 = pb[512 + j1];
  }
  int pcur = b * 1024;
  __syncthreads();

  #pragma unroll 1
  for (int s = 0; s < S_LEN; ++s) {
    unsigned short nzx0 = 0, nzx1 = 0, nrx0 = 0, nrx1 = 0, ncx0 = 0, ncx1 = 0;
    if (owner && s + 1 < S_LEN) {
      const unsigned short* pb = P + pcur + 65536;
      nzx0 = pb[j0]; nzx1 = pb[j1];
      nrx0 = pb[256 + j0]; nrx1 = pb[256 + j1];
      ncx0 = pb[512 + j0]; ncx1 = pb[512 + j1];
    }
    // ---- Phase A: z,r matvecs (B = h replicated across cols)
    f32x4 az0 = {0.f,0.f,0.f,0.f}, az1 = {0.f,0.f,0.f,0.f};
    f32x4 ar0 = {0.f,0.f,0.f,0.f}, ar1 = {0.f,0.f,0.f,0.f};
    #pragma unroll
    for (int kc = 0; kc < 8; ++kc) {
      half8v hB = *(const half8v*)((const char*)h_lds + kc * 64 + khi * 16);
      az0 = __builtin_amdgcn_mfma_f32_16x16x32_f16(wzA[0][kc], hB, az0, 0, 0, 0);
      az1 = __builtin_amdgcn_mfma_f32_16x16x32_f16(wzA[1][kc], hB, az1, 0, 0, 0);
      ar0 = __builtin_amdgcn_mfma_f32_16x16x32_f16(wrA[0][kc], hB, ar0, 0, 0, 0);
      ar1 = __builtin_amdgcn_mfma_f32_16x16x32_f16(wrA[1][kc], hB, ar1, 0, 0, 0);
    }
    float z0 = sigm(sel4(az0, lb) + uph(czx0));
    float z1 = sigm(sel4(az1, lb) + uph(czx1));
    float r0 = sigm(sel4(ar0, lb) + uph(crx0));
    float r1 = sigm(sel4(ar1, lb) + uph(crx1));
    if (owner) {
      rh_lds[j0] = f16bits(r0 * h0);
      rh_lds[j1] = f16bits(r1 * h1);
    }
    __syncthreads();                                   // (1) rh ready
    // ---- Phase C: c matvec (B = r*h replicated)
    f32x4 ac0 = {0.f,0.f,0.f,0.f}, ac1 = {0.f,0.f,0.f,0.f};
    #pragma unroll
    for (int kc = 0; kc < 8; ++kc) {
      half8v rB = *(const half8v*)((const char*)rh_lds + kc * 64 + khi * 16);
      ac0 = __builtin_amdgcn_mfma_f32_16x16x32_f16(wcA[0][kc], rB, ac0, 0, 0, 0);
      ac1 = __builtin_amdgcn_mfma_f32_16x16x32_f16(wcA[1][kc], rB, ac1, 0, 0, 0);
    }
    float ht0 = tanh_fast(sel4(ac0, lb) + uph(ccx0));
    float ht1 = tanh_fast(sel4(ac1, lb) + uph(ccx1));
    float hn0 = (1.f - z0) * h0 + z0 * ht0;
    float hn1 = (1.f - z1) * h1 + z1 * ht1;
    h0 = hn0; h1 = hn1;
    if (owner) {
      unsigned short b0 = f16bits(hn0), b1 = f16bits(hn1);
      h_lds[j0] = b0; h_lds[j1] = b1;
      P[pcur + j0] = b0; P[pcur + j1] = b1;
    }
    czx0 = nzx0; czx1 = nzx1; crx0 = nrx0; crx1 = nrx1; ccx0 = ncx0; ccx1 = ncx1;
    pcur += 65536;
    __syncthreads();                                   // (2) h ready
  }
  if (owner) {
    out[(size_t)33554432 + b * 256 + j0] = h0;
    out[(size_t)33554432 + b * 256 + j1] = h1;
  }
}

// ---------------------------------------------------------------------------
// Kernel 3: g-gate + highway + LayerNorm as MFMA GEMM. (unchanged from R5)
// ---------------------------------------------------------------------------
__global__ __launch_bounds__(512, 2) void g_mfma_ln(
    const float* __restrict__ Wh,
    const float* __restrict__ gamma, const float* __restrict__ beta,
    const unsigned short* __restrict__ P,
    float* __restrict__ out)
{
  __shared__ __align__(16) char As[128 * 128];    // hprev tile f16 (swizzled)
  __shared__ __align__(16) char Bs[256 * 128];    // Wg tile f16 (swizzled)
  __shared__ float red1[128][4];
  __shared__ float red2[128][4];
  __shared__ float2 murs[128];

  const int t = threadIdx.x;
  const int lane = t & 63;
  const int wid = t >> 6;
  const int wm = wid >> 2, wn = wid & 3;          // 2 x 4 wave grid
  const unsigned m0 = blockIdx.x * 128;

  float gam4[4], bet4[4];
  #pragma unroll
  for (int jq = 0; jq < 4; ++jq) {
    int col = wn * 64 + jq * 16 + (lane & 15);
    gam4[jq] = gamma[col];
    bet4[jq] = beta[col];
  }

  f32x4 acc[4][4];
  #pragma unroll
  for (int i = 0; i < 4; ++i)
    #pragma unroll
    for (int jq = 0; jq < 4; ++jq) acc[i][jq] = f32x4{0.f, 0.f, 0.f, 0.f};

  for (int kk = 0; kk < 4; ++kk) {
    __syncthreads();
    #pragma unroll
    for (int it = 0; it < 2; ++it) {
      int g = it * 512 + t;
      int row = g >> 3;
      int c8 = g & 7;
      int msrc = (int)m0 + row - 64;
      uint4 v = uint4{0u, 0u, 0u, 0u};
      if (msrc >= 0) v = *(const uint4*)(P + (unsigned)msrc * 1024 + kk * 64 + c8 * 8);
      *(uint4*)(As + row * 128 + ((c8 * 16) ^ ((row & 7) << 4))) = v;
    }
    #pragma unroll
    for (int it = 0; it < 4; ++it) {
      int g = it * 512 + t;
      int row = g >> 3;
      int c8 = g & 7;
      const float* src = Wh + row * 512 + 256 + kk * 64 + c8 * 8;
      f32x4 v0 = *(const f32x4*)(src);
      f32x4 v1 = *(const f32x4*)(src + 4);
      uint4 pw;
      pw.x = pk16(v0[0], v0[1]); pw.y = pk16(v0[2], v0[3]);
      pw.z = pk16(v1[0], v1[1]); pw.w = pk16(v1[2], v1[3]);
      *(uint4*)(Bs + row * 128 + ((c8 * 16) ^ ((row & 7) << 4))) = pw;
    }
    __syncthreads();
    #pragma unroll
    for (int k2 = 0; k2 < 2; ++k2) {
      const int kb = k2 * 64 + (lane >> 4) * 16;
      half8v a[4], bfr[4];
      #pragma unroll
      for (int i = 0; i < 4; ++i) {
        int ar = wm * 64 + i * 16 + (lane & 15);
        a[i] = *(const half8v*)(As + ar * 128 + (kb ^ ((ar & 7) << 4)));
        int br2 = wn * 64 + i * 16 + (lane & 15);
        bfr[i] = *(const half8v*)(Bs + br2 * 128 + (kb ^ ((br2 & 7) << 4)));
      }
      #pragma unroll
      for (int i = 0; i < 4; ++i)
        #pragma unroll
        for (int jq = 0; jq < 4; ++jq)
          acc[i][jq] = __builtin_amdgcn_mfma_f32_16x16x32_f16(a[i], bfr[jq], acc[i][jq], 0, 0, 0);
    }
  }

  #pragma unroll
  for (int i = 0; i < 4; ++i) {
    #pragma unroll
    for (int r = 0; r < 4; ++r) {
      unsigned mm = m0 + wm * 64 + i * 16 + ((lane >> 4) << 2) + r;
      unsigned bse = mm << 10;
      unsigned bsp = (mm - 64) << 10;
      #pragma unroll
      for (int jq = 0; jq < 4; ++jq) {
        int col2 = wn * 64 + jq * 16 + (lane & 15);
        float gx = uph(P[bse + 768 + col2]);
        float hnew = uph(P[bse + col2]);
        float hp = (mm >= 64) ? uph(P[bsp + col2]) : 0.f;
        float g = sigm(acc[i][jq][r] + gx);
        acc[i][jq][r] = g * hnew + (1.f - g) * hp;
      }
    }
  }
  #pragma unroll
  for (int i = 0; i < 4; ++i) {
    #pragma unroll
    for (int r = 0; r < 4; ++r) {
      float s1 = acc[i][0][r] + acc[i][1][r] + acc[i][2][r] + acc[i][3][r];
      float s2 = acc[i][0][r]*acc[i][0][r] + acc[i][1][r]*acc[i][1][r]
               + acc[i][2][r]*acc[i][2][r] + acc[i][3][r]*acc[i][3][r];
      s1 += __shfl_xor(s1, 1); s2 += __shfl_xor(s2, 1);
      s1 += __shfl_xor(s1, 2); s2 += __shfl_xor(s2, 2);
      s1 += __shfl_xor(s1, 4); s2 += __shfl_xor(s2, 4);
      s1 += __shfl_xor(s1, 8); s2 += __shfl_xor(s2, 8);
      if ((lane & 15) == 0) {
        int rowl = wm * 64 + i * 16 + ((lane >> 4) << 2) + r;
        red1[rowl][wn] = s1;
        red2[rowl][wn] = s2;
      }
    }
  }
  __syncthreads();
  if (t < 128) {
    float S1 = red1[t][0] + red1[t][1] + red1[t][2] + red1[t][3];
    float S2 = red2[t][0] + red2[t][1] + red2[t][2] + red2[t][3];
    float mu = S1 * (1.0f / 256.0f);
    float var = S2 * (1.0f / 256.0f) - mu * mu;
    murs[t] = make_float2(mu, rsqrtf(var + 1e-5f));
  }
  __syncthreads();
  #pragma unroll
  for (int i = 0; i < 4; ++i) {
    #pragma unroll
    for (int r = 0; r < 4; ++r) {
      int rowl = wm * 64 + i * 16 + ((lane >> 4) << 2) + r;
      float2 mr = murs[rowl];
      unsigned mm = m0 + rowl;
      #pragma unroll
      for (int jq = 0; jq < 4; ++jq) {
        int col2 = wn * 64 + jq * 16 + (lane & 15);
        out[(size_t)mm * 256 + col2] = (acc[i][jq][r] - mr.x) * mr.y * gam4[jq] + bet4[jq];
      }
    }
  }
}

extern "C" void kernel_launch(void* const* d_in, const int* in_sizes, int n_in,
                              void* d_out, int out_size, void* d_ws, size_t ws_size,
                              hipStream_t stream) {
  const float* x  = (const float*)d_in[0];
  const float* Wz = (const float*)d_in[1];
  const float* bz = (const float*)d_in[2];
  const float* Wr = (const float*)d_in[3];
  const float* br = (const float*)d_in[4];
  const float* Wc = (const float*)d_in[5];
  const float* bc = (const float*)d_in[6];
  const float* Wh = (const float*)d_in[7];
  const float* bh = (const float*)d_in[8];
  const float* gamma = (const float*)d_in[9];
  const float* beta  = (const float*)d_in[10];
  unsigned short* P = (unsigned short*)d_ws;   // 131072 x 1024 f16 = 256 MB
  float* out = (float*)d_out;

  dim3 g1(8, 1024);
  gemm_pre<<<g1, 256, 0, stream>>>(x, Wz, bz, Wr, br, Wc, bc, Wh, bh, P);
  gru_scan<<<64, 512, 0, stream>>>(Wz, Wr, Wc, P, out);
  g_mfma_ln<<<1024, 512, 0, stream>>>(Wh, gamma, beta, P, out);
}

// Round 7
// 3564.116 us; speedup vs baseline: 1.0081x; 1.0081x over previous
//
#include <hip/hip_runtime.h>

typedef _Float16 half2v __attribute__((ext_vector_type(2)));
typedef _Float16 half8v __attribute__((ext_vector_type(8)));
typedef float f32x4 __attribute__((ext_vector_type(4)));

#define S_LEN 2048

// barrier that drains ONLY LDS counters: global loads/stores stay in flight
// (safe: all cross-wave communication in gru_scan is through LDS; the global
// prefetch loads are consumed a full step later and the P stores are never
// read back within the kernel)
#define LDS_BARRIER() asm volatile("s_waitcnt lgkmcnt(0)\n\ts_barrier" ::: "memory")

static __device__ __forceinline__ unsigned int pk16(float a, float b) {
  half2v h; h[0] = (_Float16)a; h[1] = (_Float16)b;
  return __builtin_bit_cast(unsigned int, h);
}
static __device__ __forceinline__ float uph(unsigned short u) {
  return (float)__builtin_bit_cast(_Float16, u);
}
static __device__ __forceinline__ unsigned short f16bits(float x) {
  return __builtin_bit_cast(unsigned short, (_Float16)x);
}
static __device__ __forceinline__ float sigm(float x) {
  return 1.0f / (1.0f + __expf(-x));
}
static __device__ __forceinline__ float tanh_fast(float x) {
  float e = __expf(2.0f * x);
  return 1.0f - 2.0f / (e + 1.0f);   // safe at +/-inf
}
static __device__ __forceinline__ float sel4(f32x4 v, int b) {
  return (b == 0) ? v[0] : (b == 1) ? v[1] : (b == 2) ? v[2] : v[3];
}

// ---------------------------------------------------------------------------
// Kernel 1: P[m, g*256+j] = f16( x[m,:] . W{g}_x[j,:] + b{g}[j] )  (unchanged)
// ---------------------------------------------------------------------------
__global__ __launch_bounds__(256, 2) void gemm_pre(
    const float* __restrict__ x,
    const float* __restrict__ Wz, const float* __restrict__ bz,
    const float* __restrict__ Wr, const float* __restrict__ br,
    const float* __restrict__ Wc, const float* __restrict__ bc,
    const float* __restrict__ Wh, const float* __restrict__ bh,
    unsigned short* __restrict__ P)
{
  __shared__ __align__(16) char As[128 * 128];
  __shared__ __align__(16) char Bs[128 * 128];
  const int t = threadIdx.x;
  const int lane = t & 63;
  const int wid = t >> 6;
  const int wm = wid >> 1, wn = wid & 1;
  const int n0 = blockIdx.x * 128;
  const int m0 = blockIdx.y * 128;

  f32x4 acc[4][4];
  #pragma unroll
  for (int i = 0; i < 4; ++i)
    #pragma unroll
    for (int jq = 0; jq < 4; ++jq) acc[i][jq] = f32x4{0.f, 0.f, 0.f, 0.f};

  for (int kk = 0; kk < 4; ++kk) {
    __syncthreads();
    #pragma unroll
    for (int it = 0; it < 8; ++it) {
      int fl = it * 256 + t;
      int row = fl >> 4;
      int c4 = fl & 15;
      f32x4 v = *(const f32x4*)(x + (size_t)(m0 + row) * 256 + kk * 64 + c4 * 4);
      uint2 pw; pw.x = pk16(v[0], v[1]); pw.y = pk16(v[2], v[3]);
      *(uint2*)(As + row * 128 + ((c4 * 8) ^ ((row & 7) << 4))) = pw;

      int n = n0 + row;
      int g = n >> 8; int jc = n & 255;
      const float* W = (g == 0) ? Wz : (g == 1) ? Wr : (g == 2) ? Wc : Wh;
      f32x4 wv = *(const f32x4*)(W + jc * 512 + kk * 64 + c4 * 4);
      uint2 qw; qw.x = pk16(wv[0], wv[1]); qw.y = pk16(wv[2], wv[3]);
      *(uint2*)(Bs + row * 128 + ((c4 * 8) ^ ((row & 7) << 4))) = qw;
    }
    __syncthreads();
    #pragma unroll
    for (int k2 = 0; k2 < 2; ++k2) {
      const int kb = k2 * 64 + (lane >> 4) * 16;
      half8v a[4], bfr[4];
      #pragma unroll
      for (int i = 0; i < 4; ++i) {
        int ar = wm * 64 + i * 16 + (lane & 15);
        a[i] = *(const half8v*)(As + ar * 128 + (kb ^ ((ar & 7) << 4)));
        int br2 = wn * 64 + i * 16 + (lane & 15);
        bfr[i] = *(const half8v*)(Bs + br2 * 128 + (kb ^ ((br2 & 7) << 4)));
      }
      #pragma unroll
      for (int i = 0; i < 4; ++i)
        #pragma unroll
        for (int jq = 0; jq < 4; ++jq)
          acc[i][jq] = __builtin_amdgcn_mfma_f32_16x16x32_f16(a[i], bfr[jq], acc[i][jq], 0, 0, 0);
    }
  }
  #pragma unroll
  for (int jq = 0; jq < 4; ++jq) {
    int col = n0 + wn * 64 + jq * 16 + (lane & 15);
    int g = col >> 8; int jc = col & 255;
    const float* bp = (g == 0) ? bz : (g == 1) ? br : (g == 2) ? bc : bh;
    float bias = bp[jc];
    #pragma unroll
    for (int i = 0; i < 4; ++i) {
      int rowb = m0 + wm * 64 + i * 16 + (lane >> 4) * 4;
      #pragma unroll
      for (int r = 0; r < 4; ++r) {
        float vv = acc[i][jq][r] + bias;
        P[(size_t)(rowb + r) * 1024 + col] = f16bits(vv);
      }
    }
  }
}

// ---------------------------------------------------------------------------
// Kernel 2: sequential scan via per-wave MFMA matvecs (R6 structure) with
// LDS-only barriers: global prefetch/stores stay in flight across steps.
// ---------------------------------------------------------------------------
__global__ __launch_bounds__(512, 1) void gru_scan(
    const float* __restrict__ Wz, const float* __restrict__ Wr,
    const float* __restrict__ Wc,
    unsigned short* P, float* __restrict__ out)
{
  __shared__ __align__(16) unsigned short h_lds[256];
  __shared__ __align__(16) unsigned short rh_lds[256];

  const int t = threadIdx.x;
  const int b = blockIdx.x;
  const int w = t >> 6;
  const int l = t & 63;
  const int col = l & 15;
  const int khi = l >> 4;          // 0..3
  const int lb = l & 3;
  const bool owner = (col < 4);
  const int j0 = w * 32 + khi * 4 + lb;
  const int j1 = j0 + 16;

  // ---- A-fragments: [group][k-chunk]; A[row=R0+col][k=kc*32+khi*8+e]
  half8v wzA[2][8], wrA[2][8], wcA[2][8];
  {
    #pragma unroll
    for (int g = 0; g < 2; ++g) {
      int row = w * 32 + g * 16 + col;
      const float* pz = Wz + row * 512 + 256 + khi * 8;
      const float* pr = Wr + row * 512 + 256 + khi * 8;
      const float* pc = Wc + row * 512 + 256 + khi * 8;
      #pragma unroll
      for (int kc = 0; kc < 8; ++kc) {
        half8v vz, vr, vc;
        #pragma unroll
        for (int e = 0; e < 8; ++e) {
          vz[e] = (_Float16)pz[kc * 32 + e];
          vr[e] = (_Float16)pr[kc * 32 + e];
          vc[e] = (_Float16)pc[kc * 32 + e];
        }
        wzA[g][kc] = vz; wrA[g][kc] = vr; wcA[g][kc] = vc;
      }
    }
  }

  if (t < 128) ((unsigned int*)h_lds)[t] = 0u;

  float h0 = 0.f, h1 = 0.f;
  unsigned short czx0 = 0, czx1 = 0, crx0 = 0, crx1 = 0, ccx0 = 0, ccx1 = 0;
  {
    const unsigned short* pb = P + b * 1024;
    czx0 = pb[j0]; czx1 = pb[j1];
    crx0 = pb[256 + j0]; crx1 = pb[256 + j1];
    ccx0 = pb[512 + j0]; ccx1 = pb[512 + j1];
  }
  int pcur = b * 1024;
  __syncthreads();

  #pragma unroll 1
  for (int s = 0; s < S_LEN; ++s) {
    unsigned short nzx0 = 0, nzx1 = 0, nrx0 = 0, nrx1 = 0, ncx0 = 0, ncx1 = 0;
    if (owner && s + 1 < S_LEN) {
      const unsigned short* pb = P + pcur + 65536;
      nzx0 = pb[j0]; nzx1 = pb[j1];
      nrx0 = pb[256 + j0]; nrx1 = pb[256 + j1];
      ncx0 = pb[512 + j0]; ncx1 = pb[512 + j1];
    }
    // ---- Phase A: r,z matvecs (B = h replicated across cols); r first —
    // the r -> sigmoid -> rh chain is the critical path into barrier (1).
    f32x4 az0 = {0.f,0.f,0.f,0.f}, az1 = {0.f,0.f,0.f,0.f};
    f32x4 ar0 = {0.f,0.f,0.f,0.f}, ar1 = {0.f,0.f,0.f,0.f};
    #pragma unroll
    for (int kc = 0; kc < 8; ++kc) {
      half8v hB = *(const half8v*)((const char*)h_lds + kc * 64 + khi * 16);
      ar0 = __builtin_amdgcn_mfma_f32_16x16x32_f16(wrA[0][kc], hB, ar0, 0, 0, 0);
      ar1 = __builtin_amdgcn_mfma_f32_16x16x32_f16(wrA[1][kc], hB, ar1, 0, 0, 0);
      az0 = __builtin_amdgcn_mfma_f32_16x16x32_f16(wzA[0][kc], hB, az0, 0, 0, 0);
      az1 = __builtin_amdgcn_mfma_f32_16x16x32_f16(wzA[1][kc], hB, az1, 0, 0, 0);
    }
    float r0 = sigm(sel4(ar0, lb) + uph(crx0));
    float r1 = sigm(sel4(ar1, lb) + uph(crx1));
    float z0 = sigm(sel4(az0, lb) + uph(czx0));
    float z1 = sigm(sel4(az1, lb) + uph(czx1));
    if (owner) {
      rh_lds[j0] = f16bits(r0 * h0);
      rh_lds[j1] = f16bits(r1 * h1);
    }
    LDS_BARRIER();                                     // (1) rh ready
    // ---- Phase C: c matvec (B = r*h replicated)
    f32x4 ac0 = {0.f,0.f,0.f,0.f}, ac1 = {0.f,0.f,0.f,0.f};
    #pragma unroll
    for (int kc = 0; kc < 8; ++kc) {
      half8v rB = *(const half8v*)((const char*)rh_lds + kc * 64 + khi * 16);
      ac0 = __builtin_amdgcn_mfma_f32_16x16x32_f16(wcA[0][kc], rB, ac0, 0, 0, 0);
      ac1 = __builtin_amdgcn_mfma_f32_16x16x32_f16(wcA[1][kc], rB, ac1, 0, 0, 0);
    }
    float ht0 = tanh_fast(sel4(ac0, lb) + uph(ccx0));
    float ht1 = tanh_fast(sel4(ac1, lb) + uph(ccx1));
    float hn0 = (1.f - z0) * h0 + z0 * ht0;
    float hn1 = (1.f - z1) * h1 + z1 * ht1;
    h0 = hn0; h1 = hn1;
    if (owner) {
      unsigned short b0 = f16bits(hn0), b1 = f16bits(hn1);
      h_lds[j0] = b0; h_lds[j1] = b1;
      P[pcur + j0] = b0; P[pcur + j1] = b1;
    }
    czx0 = nzx0; czx1 = nzx1; crx0 = nrx0; crx1 = nrx1; ccx0 = ncx0; ccx1 = ncx1;
    pcur += 65536;
    LDS_BARRIER();                                     // (2) h ready
  }
  if (owner) {
    out[(size_t)33554432 + b * 256 + j0] = h0;
    out[(size_t)33554432 + b * 256 + j1] = h1;
  }
}

// ---------------------------------------------------------------------------
// Kernel 3: g-gate + highway + LayerNorm as MFMA GEMM. (unchanged)
// ---------------------------------------------------------------------------
__global__ __launch_bounds__(512, 2) void g_mfma_ln(
    const float* __restrict__ Wh,
    const float* __restrict__ gamma, const float* __restrict__ beta,
    const unsigned short* __restrict__ P,
    float* __restrict__ out)
{
  __shared__ __align__(16) char As[128 * 128];    // hprev tile f16 (swizzled)
  __shared__ __align__(16) char Bs[256 * 128];    // Wg tile f16 (swizzled)
  __shared__ float red1[128][4];
  __shared__ float red2[128][4];
  __shared__ float2 murs[128];

  const int t = threadIdx.x;
  const int lane = t & 63;
  const int wid = t >> 6;
  const int wm = wid >> 2, wn = wid & 3;          // 2 x 4 wave grid
  const unsigned m0 = blockIdx.x * 128;

  float gam4[4], bet4[4];
  #pragma unroll
  for (int jq = 0; jq < 4; ++jq) {
    int col = wn * 64 + jq * 16 + (lane & 15);
    gam4[jq] = gamma[col];
    bet4[jq] = beta[col];
  }

  f32x4 acc[4][4];
  #pragma unroll
  for (int i = 0; i < 4; ++i)
    #pragma unroll
    for (int jq = 0; jq < 4; ++jq) acc[i][jq] = f32x4{0.f, 0.f, 0.f, 0.f};

  for (int kk = 0; kk < 4; ++kk) {
    __syncthreads();
    #pragma unroll
    for (int it = 0; it < 2; ++it) {
      int g = it * 512 + t;
      int row = g >> 3;
      int c8 = g & 7;
      int msrc = (int)m0 + row - 64;
      uint4 v = uint4{0u, 0u, 0u, 0u};
      if (msrc >= 0) v = *(const uint4*)(P + (unsigned)msrc * 1024 + kk * 64 + c8 * 8);
      *(uint4*)(As + row * 128 + ((c8 * 16) ^ ((row & 7) << 4))) = v;
    }
    #pragma unroll
    for (int it = 0; it < 4; ++it) {
      int g = it * 512 + t;
      int row = g >> 3;
      int c8 = g & 7;
      const float* src = Wh + row * 512 + 256 + kk * 64 + c8 * 8;
      f32x4 v0 = *(const f32x4*)(src);
      f32x4 v1 = *(const f32x4*)(src + 4);
      uint4 pw;
      pw.x = pk16(v0[0], v0[1]); pw.y = pk16(v0[2], v0[3]);
      pw.z = pk16(v1[0], v1[1]); pw.w = pk16(v1[2], v1[3]);
      *(uint4*)(Bs + row * 128 + ((c8 * 16) ^ ((row & 7) << 4))) = pw;
    }
    __syncthreads();
    #pragma unroll
    for (int k2 = 0; k2 < 2; ++k2) {
      const int kb = k2 * 64 + (lane >> 4) * 16;
      half8v a[4], bfr[4];
      #pragma unroll
      for (int i = 0; i < 4; ++i) {
        int ar = wm * 64 + i * 16 + (lane & 15);
        a[i] = *(const half8v*)(As + ar * 128 + (kb ^ ((ar & 7) << 4)));
        int br2 = wn * 64 + i * 16 + (lane & 15);
        bfr[i] = *(const half8v*)(Bs + br2 * 128 + (kb ^ ((br2 & 7) << 4)));
      }
      #pragma unroll
      for (int i = 0; i < 4; ++i)
        #pragma unroll
        for (int jq = 0; jq < 4; ++jq)
          acc[i][jq] = __builtin_amdgcn_mfma_f32_16x16x32_f16(a[i], bfr[jq], acc[i][jq], 0, 0, 0);
    }
  }

  #pragma unroll
  for (int i = 0; i < 4; ++i) {
    #pragma unroll
    for (int r = 0; r < 4; ++r) {
      unsigned mm = m0 + wm * 64 + i * 16 + ((lane >> 4) << 2) + r;
      unsigned bse = mm << 10;
      unsigned bsp = (mm - 64) << 10;
      #pragma unroll
      for (int jq = 0; jq < 4; ++jq) {
        int col2 = wn * 64 + jq * 16 + (lane & 15);
        float gx = uph(P[bse + 768 + col2]);
        float hnew = uph(P[bse + col2]);
        float hp = (mm >= 64) ? uph(P[bsp + col2]) : 0.f;
        float g = sigm(acc[i][jq][r] + gx);
        acc[i][jq][r] = g * hnew + (1.f - g) * hp;
      }
    }
  }
  #pragma unroll
  for (int i = 0; i < 4; ++i) {
    #pragma unroll
    for (int r = 0; r < 4; ++r) {
      float s1 = acc[i][0][r] + acc[i][1][r] + acc[i][2][r] + acc[i][3][r];
      float s2 = acc[i][0][r]*acc[i][0][r] + acc[i][1][r]*acc[i][1][r]
               + acc[i][2][r]*acc[i][2][r] + acc[i][3][r]*acc[i][3][r];
      s1 += __shfl_xor(s1, 1); s2 += __shfl_xor(s2, 1);
      s1 += __shfl_xor(s1, 2); s2 += __shfl_xor(s2, 2);
      s1 += __shfl_xor(s1, 4); s2 += __shfl_xor(s2, 4);
      s1 += __shfl_xor(s1, 8); s2 += __shfl_xor(s2, 8);
      if ((lane & 15) == 0) {
        int rowl = wm * 64 + i * 16 + ((lane >> 4) << 2) + r;
        red1[rowl][wn] = s1;
        red2[rowl][wn] = s2;
      }
    }
  }
  __syncthreads();
  if (t < 128) {
    float S1 = red1[t][0] + red1[t][1] + red1[t][2] + red1[t][3];
    float S2 = red2[t][0] + red2[t][1] + red2[t][2] + red2[t][3];
    float mu = S1 * (1.0f / 256.0f);
    float var = S2 * (1.0f / 256.0f) - mu * mu;
    murs[t] = make_float2(mu, rsqrtf(var + 1e-5f));
  }
  __syncthreads();
  #pragma unroll
  for (int i = 0; i < 4; ++i) {
    #pragma unroll
    for (int r = 0; r < 4; ++r) {
      int rowl = wm * 64 + i * 16 + ((lane >> 4) << 2) + r;
      float2 mr = murs[rowl];
      unsigned mm = m0 + rowl;
      #pragma unroll
      for (int jq = 0; jq < 4; ++jq) {
        int col2 = wn * 64 + jq * 16 + (lane & 15);
        out[(size_t)mm * 256 + col2] = (acc[i][jq][r] - mr.x) * mr.y * gam4[jq] + bet4[jq];
      }
    }
  }
}

extern "C" void kernel_launch(void* const* d_in, const int* in_sizes, int n_in,
                              void* d_out, int out_size, void* d_ws, size_t ws_size,
                              hipStream_t stream) {
  const float* x  = (const float*)d_in[0];
  const float* Wz = (const float*)d_in[1];
  const float* bz = (const float*)d_in[2];
  const float* Wr = (const float*)d_in[3];
  const float* br = (const float*)d_in[4];
  const float* Wc = (const float*)d_in[5];
  const float* bc = (const float*)d_in[6];
  const float* Wh = (const float*)d_in[7];
  const float* bh = (const float*)d_in[8];
  const float* gamma = (const float*)d_in[9];
  const float* beta  = (const float*)d_in[10];
  unsigned short* P = (unsigned short*)d_ws;   // 131072 x 1024 f16 = 256 MB
  float* out = (float*)d_out;

  dim3 g1(8, 1024);
  gemm_pre<<<g1, 256, 0, stream>>>(x, Wz, bz, Wr, br, Wc, bc, Wh, bh, P);
  gru_scan<<<64, 512, 0, stream>>>(Wz, Wr, Wc, P, out);
  g_mfma_ln<<<1024, 512, 0, stream>>>(Wh, gamma, beta, P, out);
}